// Round 3
// baseline (2079.766 us; speedup 1.0000x reference)
//
#include <hip/hip_runtime.h>
#include <hip/hip_bf16.h>
#include <stdint.h>

// Problem constants
#define BB 2
#define NN 2048
#define DIM 4096
#define NH 32
#define NKV 8
#define HD 128

typedef __attribute__((ext_vector_type(8))) short short8;
typedef __attribute__((ext_vector_type(4))) float floatx4;

__device__ __forceinline__ float bf2f(uint16_t u) {
  union { uint32_t u; float f; } c; c.u = ((uint32_t)u) << 16; return c.f;
}
__device__ __forceinline__ uint16_t f2bf(float f) {
  union { float f; uint32_t u; } c; c.f = f;
  uint32_t u = c.u;
  return (uint16_t)((u + 0x7fffu + ((u >> 16) & 1u)) >> 16);
}

// Load 8 consecutive elements (f32 or bf16 source) -> 8 bf16 into LDS (16B).
template <bool F32>
__device__ __forceinline__ void load8(const void* __restrict__ base, size_t off,
                                      uint16_t* __restrict__ lds) {
  if constexpr (F32) {
    const float* p = (const float*)base + off;
    float4 a = *(const float4*)p;
    float4 b = *(const float4*)(p + 4);
    uint16_t t[8];
    t[0] = f2bf(a.x); t[1] = f2bf(a.y); t[2] = f2bf(a.z); t[3] = f2bf(a.w);
    t[4] = f2bf(b.x); t[5] = f2bf(b.y); t[6] = f2bf(b.z); t[7] = f2bf(b.w);
    *(float4*)lds = *(float4*)t;
  } else {
    *(float4*)lds = *(const float4*)((const uint16_t*)base + off);
  }
}

// ---------------------------------------------------------------------------
// C[m,n] = sum_k A[m,k] * B[n,k]   (A: MxK, B: NxK, row-major)
// 128x128 tile, 4 waves (2x2), each wave 64x64 = 4x4 mfma_f32_16x16x32_bf16
// AF32/BF32: operand dtype (f32 converted to bf16 at staging). CF32: out dtype.
// ---------------------------------------------------------------------------
template <bool AF32, bool BF32, bool CF32>
__global__ __launch_bounds__(256) void gemm_bt(const void* __restrict__ Av,
                                               const void* __restrict__ Bv,
                                               void* __restrict__ Cv,
                                               int M, int N, int K) {
  __shared__ __align__(16) uint16_t As[128 * 32];
  __shared__ __align__(16) uint16_t Bs[128 * 32];
  const int tid = threadIdx.x;
  const int wave = tid >> 6, lane = tid & 63;
  const int quad = lane >> 4, l16 = lane & 15;
  const int m0 = blockIdx.y * 128, n0 = blockIdx.x * 128;
  const int wm = (wave >> 1) * 64, wn = (wave & 1) * 64;

  floatx4 acc[4][4] = {};

  for (int kb = 0; kb < K; kb += 32) {
    int s = tid;
#pragma unroll
    for (int i = 0; i < 2; ++i, s += 256) {
      int row = s >> 2, cs = (s & 3) * 8;
      load8<AF32>(Av, (size_t)(m0 + row) * K + kb + cs, &As[row * 32 + cs]);
      load8<BF32>(Bv, (size_t)(n0 + row) * K + kb + cs, &Bs[row * 32 + cs]);
    }
    __syncthreads();

    short8 a[4], b[4];
#pragma unroll
    for (int i = 0; i < 4; ++i)
      a[i] = *(const short8*)(&As[(wm + i * 16 + l16) * 32 + quad * 8]);
#pragma unroll
    for (int j = 0; j < 4; ++j)
      b[j] = *(const short8*)(&Bs[(wn + j * 16 + l16) * 32 + quad * 8]);
#pragma unroll
    for (int i = 0; i < 4; ++i)
#pragma unroll
      for (int j = 0; j < 4; ++j)
        acc[i][j] = __builtin_amdgcn_mfma_f32_16x16x32_bf16(a[i], b[j], acc[i][j], 0, 0, 0);
    __syncthreads();
  }

  // epilogue: C/D layout row = quad*4 + r, col = l16
#pragma unroll
  for (int i = 0; i < 4; ++i) {
#pragma unroll
    for (int r = 0; r < 4; ++r) {
      int row = m0 + wm + i * 16 + quad * 4 + r;
#pragma unroll
      for (int j = 0; j < 4; ++j) {
        int col = n0 + wn + j * 16 + l16;
        if constexpr (CF32)
          ((float*)Cv)[(size_t)row * N + col] = acc[i][j][r];
        else
          ((uint16_t*)Cv)[(size_t)row * N + col] = f2bf(acc[i][j][r]);
      }
    }
  }
}

// ---------------------------------------------------------------------------
// RoPE in-place on (B*N, H, 128) bf16. cos/sin are float32 (N, 64).
// ---------------------------------------------------------------------------
__global__ void rope_kernel(uint16_t* __restrict__ qk,
                            const float* __restrict__ cosb,
                            const float* __restrict__ sinb, int H, int total) {
  int idx = blockIdx.x * blockDim.x + threadIdx.x;
  if (idx >= total) return;
  int p = idx & 63;
  int nh = idx >> 6;       // (b*N + n)*H + h
  int bn = nh / H;
  int n = bn & (NN - 1);
  size_t base = (size_t)nh * 128 + p * 2;
  uint32_t pr = *(const uint32_t*)(&qk[base]);
  float x0 = bf2f((uint16_t)(pr & 0xffff));
  float x1 = bf2f((uint16_t)(pr >> 16));
  float c = cosb[n * 64 + p];
  float s = sinb[n * 64 + p];
  float o0 = x0 * c - x1 * s;
  float o1 = x0 * s + x1 * c;
  *(uint32_t*)(&qk[base]) = (uint32_t)f2bf(o0) | ((uint32_t)f2bf(o1) << 16);
}

// ---------------------------------------------------------------------------
// Flash attention (causal, GQA). Block = (qtile of 64 rows, head, batch).
// 4 waves; wave w owns q rows [q0+16w, q0+16w+16). Online softmax per row.
// ---------------------------------------------------------------------------
__global__ __launch_bounds__(256) void flash_attn(const uint16_t* __restrict__ Q,
                                                  const uint16_t* __restrict__ K,
                                                  const uint16_t* __restrict__ V,
                                                  uint16_t* __restrict__ O) {
  __shared__ __align__(16) uint16_t Ks[64 * 128];   // [kv][d]
  __shared__ __align__(16) uint16_t Vt[128 * 64];   // [d][kv]
  __shared__ __align__(16) uint16_t Ps[4][16 * 64]; // per-wave P, [qrow][kv]

  const int tid = threadIdx.x;
  const int wave = tid >> 6, lane = tid & 63;
  const int quad = lane >> 4, l16 = lane & 15;
  const int b = blockIdx.z, h = blockIdx.y, kvh = h >> 2;
  const int q0 = blockIdx.x * 64;
  const int qw = q0 + wave * 16;

  // Q fragments: A[m=l16][k = kd*32 + quad*8 + j]
  short8 aq[4];
  {
    const uint16_t* qrow = Q + (((size_t)(b * NN + qw + l16)) * NH + h) * HD;
#pragma unroll
    for (int kd = 0; kd < 4; ++kd)
      aq[kd] = *(const short8*)(&qrow[kd * 32 + quad * 8]);
  }

  float mr[4], lr[4];
  floatx4 accO[8] = {};
#pragma unroll
  for (int r = 0; r < 4; ++r) { mr[r] = -1e30f; lr[r] = 0.f; }

  const float scale = 0.08838834764831845f; // 1/sqrt(128)
  const int ntiles = blockIdx.x + 1;

  for (int t = 0; t < ntiles; ++t) {
    const int kv0 = t * 64;
#pragma unroll
    for (int i = 0; i < 4; ++i) {
      int c = tid + i * 256;
      int row = c >> 4, d8 = (c & 15) * 8;
      size_t gbase = (((size_t)(b * NN + kv0 + row)) * NKV + kvh) * HD + d8;
      *(float4*)(&Ks[row * 128 + d8]) = *(const float4*)(&K[gbase]);
      uint16_t vv[8];
      *(float4*)vv = *(const float4*)(&V[gbase]);
#pragma unroll
      for (int j = 0; j < 8; ++j) Vt[(d8 + j) * 64 + row] = vv[j];
    }
    __syncthreads();

    // S = Q K^T : wave's 16 rows x 64 cols
    floatx4 sc[4];
#pragma unroll
    for (int jn = 0; jn < 4; ++jn) {
      sc[jn] = (floatx4){0.f, 0.f, 0.f, 0.f};
#pragma unroll
      for (int kd = 0; kd < 4; ++kd) {
        short8 bk = *(const short8*)(&Ks[(jn * 16 + l16) * 128 + kd * 32 + quad * 8]);
        sc[jn] = __builtin_amdgcn_mfma_f32_16x16x32_bf16(aq[kd], bk, sc[jn], 0, 0, 0);
      }
    }

    // scale + causal mask (only diagonal tile needs the elementwise mask)
    const bool last = (t == ntiles - 1);
#pragma unroll
    for (int jn = 0; jn < 4; ++jn)
#pragma unroll
      for (int r = 0; r < 4; ++r) {
        float s = sc[jn][r] * scale;
        if (last) {
          int qr = qw + quad * 4 + r;
          int kc = kv0 + jn * 16 + l16;
          if (kc > qr) s = -1e30f;
        }
        sc[jn][r] = s;
      }

    // online softmax; rows live in 16-lane quad groups -> intra-quad shuffles
    float alpha[4];
#pragma unroll
    for (int r = 0; r < 4; ++r) {
      float mx = fmaxf(fmaxf(sc[0][r], sc[1][r]), fmaxf(sc[2][r], sc[3][r]));
#pragma unroll
      for (int off = 1; off < 16; off <<= 1)
        mx = fmaxf(mx, __shfl_xor(mx, off, 64));
      float mn = fmaxf(mr[r], mx);
      alpha[r] = __expf(mr[r] - mn);
      mr[r] = mn;
      float rs = 0.f;
#pragma unroll
      for (int jn = 0; jn < 4; ++jn) {
        float p = __expf(sc[jn][r] - mn);
        sc[jn][r] = p;
        rs += p;
      }
#pragma unroll
      for (int off = 1; off < 16; off <<= 1)
        rs += __shfl_xor(rs, off, 64);
      lr[r] = lr[r] * alpha[r] + rs;
    }

    // P (C-layout) -> LDS -> A-layout
#pragma unroll
    for (int jn = 0; jn < 4; ++jn)
#pragma unroll
      for (int r = 0; r < 4; ++r)
        Ps[wave][(quad * 4 + r) * 64 + jn * 16 + l16] = f2bf(sc[jn][r]);

    // rescale O by alpha
#pragma unroll
    for (int dt = 0; dt < 8; ++dt)
#pragma unroll
      for (int r = 0; r < 4; ++r) accO[dt][r] *= alpha[r];
    __syncthreads();

    // O += P @ V
    short8 ap[2];
#pragma unroll
    for (int kk = 0; kk < 2; ++kk)
      ap[kk] = *(const short8*)(&Ps[wave][l16 * 64 + kk * 32 + quad * 8]);
#pragma unroll
    for (int dt = 0; dt < 8; ++dt) {
#pragma unroll
      for (int kk = 0; kk < 2; ++kk) {
        short8 bv = *(const short8*)(&Vt[(dt * 16 + l16) * 64 + kk * 32 + quad * 8]);
        accO[dt] = __builtin_amdgcn_mfma_f32_16x16x32_bf16(ap[kk], bv, accO[dt], 0, 0, 0);
      }
    }
    __syncthreads();
  }

  // epilogue: O /= l
#pragma unroll
  for (int r = 0; r < 4; ++r) lr[r] = 1.f / lr[r];
#pragma unroll
  for (int dt = 0; dt < 8; ++dt)
#pragma unroll
    for (int r = 0; r < 4; ++r) {
      int qr = qw + quad * 4 + r;
      size_t oidx = (((size_t)(b * NN + qr)) * NH + h) * HD + dt * 16 + l16;
      O[oidx] = f2bf(accO[dt][r] * lr[r]);
    }
}

// ---------------------------------------------------------------------------
extern "C" void kernel_launch(void* const* d_in, const int* in_sizes, int n_in,
                              void* d_out, int out_size, void* d_ws, size_t ws_size,
                              hipStream_t stream) {
  const float* x    = (const float*)d_in[0];
  const float* wq   = (const float*)d_in[1];
  const float* wk   = (const float*)d_in[2];
  const float* wv   = (const float*)d_in[3];
  const float* wo   = (const float*)d_in[4];
  const float* cosb = (const float*)d_in[5];
  const float* sinb = (const float*)d_in[6];
  // d_in[7] = mask (computed inline), d_in[8] = start_pos (== 0, unused)
  float* out = (float*)d_out;

  const size_t M = (size_t)BB * NN;            // 4096
  uint16_t* qbuf = (uint16_t*)d_ws;            // M*DIM bf16
  uint16_t* kbuf = qbuf + M * DIM;             // M*NKV*HD
  uint16_t* vbuf = kbuf + M * NKV * HD;
  uint16_t* obuf = vbuf + M * NKV * HD;        // M*DIM

  dim3 blk(256);

  // Q/K/V projections: f32 x, f32 w -> bf16 intermediates
  gemm_bt<true, true, false><<<dim3(DIM / 128, M / 128), blk, 0, stream>>>(x, wq, qbuf, M, DIM, DIM);
  gemm_bt<true, true, false><<<dim3((NKV * HD) / 128, M / 128), blk, 0, stream>>>(x, wk, kbuf, M, NKV * HD, DIM);
  gemm_bt<true, true, false><<<dim3((NKV * HD) / 128, M / 128), blk, 0, stream>>>(x, wv, vbuf, M, NKV * HD, DIM);

  // RoPE on Q and K
  int totq = (int)(M * NH * 64);
  int totk = (int)(M * NKV * 64);
  rope_kernel<<<(totq + 255) / 256, blk, 0, stream>>>(qbuf, cosb, sinb, NH, totq);
  rope_kernel<<<(totk + 255) / 256, blk, 0, stream>>>(kbuf, cosb, sinb, NKV, totk);

  // causal GQA flash attention (bf16 in/out)
  flash_attn<<<dim3(NN / 64, NH, BB), blk, 0, stream>>>(qbuf, kbuf, vbuf, obuf);

  // output projection: bf16 attn-out, f32 wo -> f32 final
  gemm_bt<false, true, true><<<dim3(DIM / 128, M / 128), blk, 0, stream>>>(obuf, wo, out, M, DIM, DIM);
}

// Round 4
// 1085.898 us; speedup vs baseline: 1.9152x; 1.9152x over previous
//
#include <hip/hip_runtime.h>
#include <hip/hip_bf16.h>
#include <stdint.h>

// Problem constants
#define BB 2
#define NN 2048
#define DIM 4096
#define NH 32
#define NKV 8
#define HD 128

typedef __attribute__((ext_vector_type(8))) short short8;
typedef __attribute__((ext_vector_type(4))) float floatx4;

__device__ __forceinline__ float bf2f(uint16_t u) {
  union { uint32_t u; float f; } c; c.u = ((uint32_t)u) << 16; return c.f;
}
__device__ __forceinline__ uint16_t f2bf(float f) {
  union { float f; uint32_t u; } c; c.f = f;
  uint32_t u = c.u;
  return (uint16_t)((u + 0x7fffu + ((u >> 16) & 1u)) >> 16);
}

// ---- async global->LDS, 16 B per lane (dest must be uniform base + lane*16)
typedef const __attribute__((address_space(1))) uint32_t* gas_t;
typedef __attribute__((address_space(3))) uint32_t* las_t;
__device__ __forceinline__ void gl2lds16(const uint16_t* g, uint16_t* l) {
  __builtin_amdgcn_global_load_lds((gas_t)(uintptr_t)g,
                                   (las_t)(uint32_t)(uintptr_t)l, 16, 0, 0);
}

// ---------------------------------------------------------------------------
// f32 -> bf16 bulk convert (4 elems/thread)
// ---------------------------------------------------------------------------
__global__ void cvt_bf16(const float* __restrict__ in, uint16_t* __restrict__ out,
                         long n4) {
  long i = (long)blockIdx.x * 256 + threadIdx.x;
  if (i >= n4) return;
  float4 v = ((const float4*)in)[i];
  uint16_t t[4] = {f2bf(v.x), f2bf(v.y), f2bf(v.z), f2bf(v.w)};
  ((uint64_t*)out)[i] = *(uint64_t*)t;
}

// ---------------------------------------------------------------------------
// GEMM core: C[m,n] = sum_k A[m,k]*B[n,k], bf16 operands, global_load_lds
// staging (m97 structure). 128x128 tile, 4 waves, 4x4 16x16x32 MFMA per wave.
// ---------------------------------------------------------------------------
template <bool CF32>
__device__ __forceinline__ void gemm_core(const uint16_t* __restrict__ A,
                                          const uint16_t* __restrict__ B,
                                          void* __restrict__ Cv,
                                          int N, int K, int m0, int n0,
                                          uint16_t* As, uint16_t* Bs) {
  const int tid = threadIdx.x;
  const int wave = tid >> 6, lane = tid & 63;
  const int quad = lane >> 4, l16 = lane & 15;
  const int wm = (wave >> 1) * 64, wn = (wave & 1) * 64;

  // staging: wave stages 32 rows of A and B; LDS dest = waveBase + lane*16B
  const int srow = wave * 32 + (lane >> 2);
  const int scol = (lane & 3) * 8;
  const uint16_t* gA = A + (size_t)(m0 + srow) * K + scol;
  const uint16_t* gB = B + (size_t)(n0 + srow) * K + scol;
  uint16_t* lA = &As[wave * 1024 + lane * 8];
  uint16_t* lB = &Bs[wave * 1024 + lane * 8];

  floatx4 acc[4][4] = {};

  for (int kb = 0; kb < K; kb += 32) {
    gl2lds16(gA + kb, lA);
    gl2lds16(gA + kb + (size_t)16 * K, lA + 16 * 32);
    gl2lds16(gB + kb, lB);
    gl2lds16(gB + kb + (size_t)16 * K, lB + 16 * 32);
    __syncthreads();

    short8 a[4], b[4];
#pragma unroll
    for (int i = 0; i < 4; ++i)
      a[i] = *(const short8*)(&As[(wm + i * 16 + l16) * 32 + quad * 8]);
#pragma unroll
    for (int j = 0; j < 4; ++j)
      b[j] = *(const short8*)(&Bs[(wn + j * 16 + l16) * 32 + quad * 8]);
#pragma unroll
    for (int i = 0; i < 4; ++i)
#pragma unroll
      for (int j = 0; j < 4; ++j)
        acc[i][j] = __builtin_amdgcn_mfma_f32_16x16x32_bf16(a[i], b[j], acc[i][j], 0, 0, 0);
    __syncthreads();
  }

#pragma unroll
  for (int i = 0; i < 4; ++i)
#pragma unroll
    for (int r = 0; r < 4; ++r) {
      int row = m0 + wm + i * 16 + quad * 4 + r;
#pragma unroll
      for (int j = 0; j < 4; ++j) {
        int col = n0 + wn + j * 16 + l16;
        if constexpr (CF32)
          ((float*)Cv)[(size_t)row * N + col] = acc[i][j][r];
        else
          ((uint16_t*)Cv)[(size_t)row * N + col] = f2bf(acc[i][j][r]);
      }
    }
}

template <bool CF32>
__global__ __launch_bounds__(256) void gemm_fast(const uint16_t* __restrict__ A,
                                                 const uint16_t* __restrict__ B,
                                                 void* __restrict__ Cv,
                                                 int N, int K) {
  __shared__ __align__(16) uint16_t As[128 * 32];
  __shared__ __align__(16) uint16_t Bs[128 * 32];
  gemm_core<CF32>(A, B, Cv, N, K, blockIdx.y * 128, blockIdx.x * 128, As, Bs);
}

// K and V projections fused (N=1024 each) for better CU fill (512 blocks).
__global__ __launch_bounds__(256) void gemm_kv(const uint16_t* __restrict__ A,
                                               const uint16_t* __restrict__ WK,
                                               const uint16_t* __restrict__ WV,
                                               uint16_t* __restrict__ KO,
                                               uint16_t* __restrict__ VO) {
  __shared__ __align__(16) uint16_t As[128 * 32];
  __shared__ __align__(16) uint16_t Bs[128 * 32];
  const int half = blockIdx.x >> 3;
  const uint16_t* B = half ? WV : WK;
  uint16_t* C = half ? VO : KO;
  gemm_core<false>(A, B, C, 1024, DIM, blockIdx.y * 128, (blockIdx.x & 7) * 128, As, Bs);
}

// ---------------------------------------------------------------------------
// Fallback GEMM (f32 operands staged+converted in VALU) — R3-proven path,
// used only if workspace is too small for the bf16 pre-conversion buffers.
// ---------------------------------------------------------------------------
template <bool F32>
__device__ __forceinline__ void load8(const void* __restrict__ base, size_t off,
                                      uint16_t* __restrict__ lds) {
  if constexpr (F32) {
    const float* p = (const float*)base + off;
    float4 a = *(const float4*)p;
    float4 b = *(const float4*)(p + 4);
    uint16_t t[8];
    t[0] = f2bf(a.x); t[1] = f2bf(a.y); t[2] = f2bf(a.z); t[3] = f2bf(a.w);
    t[4] = f2bf(b.x); t[5] = f2bf(b.y); t[6] = f2bf(b.z); t[7] = f2bf(b.w);
    *(float4*)lds = *(float4*)t;
  } else {
    *(float4*)lds = *(const float4*)((const uint16_t*)base + off);
  }
}

template <bool AF32, bool BF32, bool CF32>
__global__ __launch_bounds__(256) void gemm_bt(const void* __restrict__ Av,
                                               const void* __restrict__ Bv,
                                               void* __restrict__ Cv,
                                               int M, int N, int K) {
  __shared__ __align__(16) uint16_t As[128 * 32];
  __shared__ __align__(16) uint16_t Bs[128 * 32];
  const int tid = threadIdx.x;
  const int wave = tid >> 6, lane = tid & 63;
  const int quad = lane >> 4, l16 = lane & 15;
  const int m0 = blockIdx.y * 128, n0 = blockIdx.x * 128;
  const int wm = (wave >> 1) * 64, wn = (wave & 1) * 64;

  floatx4 acc[4][4] = {};

  for (int kb = 0; kb < K; kb += 32) {
    int s = tid;
#pragma unroll
    for (int i = 0; i < 2; ++i, s += 256) {
      int row = s >> 2, cs = (s & 3) * 8;
      load8<AF32>(Av, (size_t)(m0 + row) * K + kb + cs, &As[row * 32 + cs]);
      load8<BF32>(Bv, (size_t)(n0 + row) * K + kb + cs, &Bs[row * 32 + cs]);
    }
    __syncthreads();

    short8 a[4], b[4];
#pragma unroll
    for (int i = 0; i < 4; ++i)
      a[i] = *(const short8*)(&As[(wm + i * 16 + l16) * 32 + quad * 8]);
#pragma unroll
    for (int j = 0; j < 4; ++j)
      b[j] = *(const short8*)(&Bs[(wn + j * 16 + l16) * 32 + quad * 8]);
#pragma unroll
    for (int i = 0; i < 4; ++i)
#pragma unroll
      for (int j = 0; j < 4; ++j)
        acc[i][j] = __builtin_amdgcn_mfma_f32_16x16x32_bf16(a[i], b[j], acc[i][j], 0, 0, 0);
    __syncthreads();
  }

#pragma unroll
  for (int i = 0; i < 4; ++i)
#pragma unroll
    for (int r = 0; r < 4; ++r) {
      int row = m0 + wm + i * 16 + quad * 4 + r;
#pragma unroll
      for (int j = 0; j < 4; ++j) {
        int col = n0 + wn + j * 16 + l16;
        if constexpr (CF32)
          ((float*)Cv)[(size_t)row * N + col] = acc[i][j][r];
        else
          ((uint16_t*)Cv)[(size_t)row * N + col] = f2bf(acc[i][j][r]);
      }
    }
}

// ---------------------------------------------------------------------------
// RoPE in-place on (B*N, H, 128) bf16. cos/sin f32 (N, 64).
// ---------------------------------------------------------------------------
__global__ void rope_kernel(uint16_t* __restrict__ qk,
                            const float* __restrict__ cosb,
                            const float* __restrict__ sinb, int H, int total) {
  int idx = blockIdx.x * blockDim.x + threadIdx.x;
  if (idx >= total) return;
  int p = idx & 63;
  int nh = idx >> 6;
  int bn = nh / H;
  int n = bn & (NN - 1);
  size_t base = (size_t)nh * 128 + p * 2;
  uint32_t pr = *(const uint32_t*)(&qk[base]);
  float x0 = bf2f((uint16_t)(pr & 0xffff));
  float x1 = bf2f((uint16_t)(pr >> 16));
  float c = cosb[n * 64 + p];
  float s = sinb[n * 64 + p];
  float o0 = x0 * c - x1 * s;
  float o1 = x0 * s + x1 * c;
  *(uint32_t*)(&qk[base]) = (uint32_t)f2bf(o0) | ((uint32_t)f2bf(o1) << 16);
}

// ---------------------------------------------------------------------------
// Flash attention (causal, GQA). Block = (128 q rows, head, batch); 4 waves,
// wave w owns rows [w*32, w*32+32). KV tile = 64. Conflict-free LDS:
//   Ks: [kv][d], row stride 136 elems (272B = 17*16B, bank-balanced)
//   Vt: [d][kv], row stride 72, kv XOR-swizzled by ((d>>3)&7)<<3
//   Ps: per-wave [qrow][kv], row stride 72
// q-tiles dispatched in descending work order (blockIdx.x reversed).
// ---------------------------------------------------------------------------
#define KSTR 136
#define VSTR 72
#define PSTR 72

__global__ __launch_bounds__(256, 2) void flash_attn(const uint16_t* __restrict__ Q,
                                                     const uint16_t* __restrict__ K,
                                                     const uint16_t* __restrict__ V,
                                                     uint16_t* __restrict__ O) {
  __shared__ __align__(16) uint16_t Ks[64 * KSTR];
  __shared__ __align__(16) uint16_t Vt[128 * VSTR];
  __shared__ __align__(16) uint16_t Ps[4][32 * PSTR];

  const int tid = threadIdx.x;
  const int wave = tid >> 6, lane = tid & 63;
  const int quad = lane >> 4, l16 = lane & 15;
  const int b = blockIdx.z, h = blockIdx.y, kvh = h >> 2;
  const int qt = gridDim.x - 1 - blockIdx.x;   // long blocks first
  const int qlo = qt * 128 + wave * 32;

  // Q fragments for 2 row-blocks of 16: A[m=l16][k=kd*32+quad*8+j]
  short8 aq[2][4];
#pragma unroll
  for (int mi = 0; mi < 2; ++mi) {
    const uint16_t* qrow = Q + (((size_t)(b * NN + qlo + mi * 16 + l16)) * NH + h) * HD;
#pragma unroll
    for (int kd = 0; kd < 4; ++kd)
      aq[mi][kd] = *(const short8*)(&qrow[kd * 32 + quad * 8]);
  }

  float mr[2][4], lr[2][4];
  floatx4 accO[2][8] = {};
#pragma unroll
  for (int mi = 0; mi < 2; ++mi)
#pragma unroll
    for (int r = 0; r < 4; ++r) { mr[mi][r] = -1e30f; lr[mi][r] = 0.f; }

  const float sc2 = 0.08838834764831845f * 1.4426950408889634f; // 1/sqrt(128)*log2e
  const int ntiles = 2 * qt + 2;

  const int srow = tid >> 4;          // staging: 16 rows per 256-thread pass
  const int sl16 = tid & 15;
  const int d8 = sl16 * 8;

  for (int t = 0; t < ntiles; ++t) {
    const int kv0 = t * 64;

    // stage K (row-major, padded) and V (transposed + swizzled)
#pragma unroll
    for (int i = 0; i < 4; ++i) {
      int row = srow + i * 16;
      size_t gb = (((size_t)(b * NN + kv0 + row)) * NKV + kvh) * HD + d8;
      *(float4*)(&Ks[row * KSTR + d8]) = *(const float4*)(&K[gb]);
      uint16_t vv[8];
      *(float4*)vv = *(const float4*)(&V[gb]);
      int kvp = row ^ ((sl16 & 7) << 3);
#pragma unroll
      for (int j = 0; j < 8; ++j) Vt[(d8 + j) * VSTR + kvp] = vv[j];
    }
    __syncthreads();

    if (kv0 <= qlo + 31) {  // tile not fully masked for this wave
      // S = Q K^T (2x4 fragments of 16x16)
      floatx4 s[2][4] = {};
#pragma unroll
      for (int jn = 0; jn < 4; ++jn)
#pragma unroll
        for (int kd = 0; kd < 4; ++kd) {
          short8 bk = *(const short8*)(&Ks[(jn * 16 + l16) * KSTR + kd * 32 + quad * 8]);
          s[0][jn] = __builtin_amdgcn_mfma_f32_16x16x32_bf16(aq[0][kd], bk, s[0][jn], 0, 0, 0);
          s[1][jn] = __builtin_amdgcn_mfma_f32_16x16x32_bf16(aq[1][kd], bk, s[1][jn], 0, 0, 0);
        }

      const bool needmask = (kv0 + 63) > qlo;
#pragma unroll
      for (int mi = 0; mi < 2; ++mi)
#pragma unroll
        for (int jn = 0; jn < 4; ++jn)
#pragma unroll
          for (int r = 0; r < 4; ++r) {
            float v = s[mi][jn][r] * sc2;   // log2 domain
            if (needmask) {
              int qr = qlo + mi * 16 + quad * 4 + r;
              int kc = kv0 + jn * 16 + l16;
              if (kc > qr) v = -1e30f;
            }
            s[mi][jn][r] = v;
          }

      // online softmax (rows live across the 16 l16-lanes of each quad)
#pragma unroll
      for (int mi = 0; mi < 2; ++mi)
#pragma unroll
        for (int r = 0; r < 4; ++r) {
          float mx = fmaxf(fmaxf(s[mi][0][r], s[mi][1][r]), fmaxf(s[mi][2][r], s[mi][3][r]));
#pragma unroll
          for (int off = 1; off < 16; off <<= 1)
            mx = fmaxf(mx, __shfl_xor(mx, off, 64));
          float mn = fmaxf(mr[mi][r], mx);
          float al = exp2f(mr[mi][r] - mn);
          mr[mi][r] = mn;
          float rs = 0.f;
#pragma unroll
          for (int jn = 0; jn < 4; ++jn) {
            float p = exp2f(s[mi][jn][r] - mn);
            s[mi][jn][r] = p;
            rs += p;
          }
#pragma unroll
          for (int off = 1; off < 16; off <<= 1)
            rs += __shfl_xor(rs, off, 64);
          lr[mi][r] = lr[mi][r] * al + rs;
#pragma unroll
          for (int jn = 0; jn < 4; ++jn)
            Ps[wave][(mi * 16 + quad * 4 + r) * PSTR + jn * 16 + l16] = f2bf(s[mi][jn][r]);
#pragma unroll
          for (int dt = 0; dt < 8; ++dt) accO[mi][dt][r] *= al;
        }

      // O += P @ V  (P via per-wave LDS round-trip; V^T swizzle-read)
      short8 ap[2][2];
#pragma unroll
      for (int mi = 0; mi < 2; ++mi)
#pragma unroll
        for (int kk = 0; kk < 2; ++kk)
          ap[mi][kk] = *(const short8*)(&Ps[wave][(mi * 16 + l16) * PSTR + kk * 32 + quad * 8]);
#pragma unroll
      for (int dt = 0; dt < 8; ++dt) {
        int x = (2 * dt + (l16 >> 3)) & 7;
#pragma unroll
        for (int kk = 0; kk < 2; ++kk) {
          int kvb = (kk * 32 + quad * 8) ^ (x << 3);
          short8 bv = *(const short8*)(&Vt[(dt * 16 + l16) * VSTR + kvb]);
          accO[0][dt] = __builtin_amdgcn_mfma_f32_16x16x32_bf16(ap[0][kk], bv, accO[0][dt], 0, 0, 0);
          accO[1][dt] = __builtin_amdgcn_mfma_f32_16x16x32_bf16(ap[1][kk], bv, accO[1][dt], 0, 0, 0);
        }
      }
    }
    __syncthreads();  // guards Ks/Vt reuse by next tile's staging
  }

#pragma unroll
  for (int mi = 0; mi < 2; ++mi)
#pragma unroll
    for (int r = 0; r < 4; ++r) lr[mi][r] = 1.f / lr[mi][r];
#pragma unroll
  for (int mi = 0; mi < 2; ++mi)
#pragma unroll
    for (int dt = 0; dt < 8; ++dt)
#pragma unroll
      for (int r = 0; r < 4; ++r) {
        int qr = qlo + mi * 16 + quad * 4 + r;
        size_t oidx = (((size_t)(b * NN + qr)) * NH + h) * HD + dt * 16 + l16;
        O[oidx] = f2bf(accO[mi][dt][r] * lr[mi][r]);
      }
}

// ---------------------------------------------------------------------------
extern "C" void kernel_launch(void* const* d_in, const int* in_sizes, int n_in,
                              void* d_out, int out_size, void* d_ws, size_t ws_size,
                              hipStream_t stream) {
  const float* x    = (const float*)d_in[0];
  const float* wq   = (const float*)d_in[1];
  const float* wk   = (const float*)d_in[2];
  const float* wv   = (const float*)d_in[3];
  const float* wo   = (const float*)d_in[4];
  const float* cosb = (const float*)d_in[5];
  const float* sinb = (const float*)d_in[6];
  float* out = (float*)d_out;

  const size_t M = (size_t)BB * NN;        // 4096
  const size_t SZ_Q = M * DIM;             // 16.78M elems
  const size_t SZ_W = (size_t)DIM * DIM;   // 16.78M
  const size_t SZ_KV = M * NKV * HD;       // 4.19M
  const size_t SZ_WKV = (size_t)NKV * HD * DIM; // 4.19M

  dim3 blk(256);
  const size_t need_fast =
      2 * (SZ_Q + 3 * SZ_W + 2 * SZ_WKV + 2 * SZ_KV + SZ_Q); // ~201 MB

  if (ws_size >= need_fast) {
    uint16_t* p = (uint16_t*)d_ws;
    uint16_t* xb   = p; p += SZ_Q;
    uint16_t* wqb  = p; p += SZ_W;
    uint16_t* wob  = p; p += SZ_W;
    uint16_t* wkb  = p; p += SZ_WKV;
    uint16_t* wvb  = p; p += SZ_WKV;
    uint16_t* qbuf = p; p += SZ_Q;
    uint16_t* kbuf = p; p += SZ_KV;
    uint16_t* vbuf = p; p += SZ_KV;
    uint16_t* obuf = p;

    // f32 -> bf16 conversions
    cvt_bf16<<<(int)(SZ_Q / 4 / 256), blk, 0, stream>>>(x, xb, SZ_Q / 4);
    cvt_bf16<<<(int)(SZ_W / 4 / 256), blk, 0, stream>>>(wq, wqb, SZ_W / 4);
    cvt_bf16<<<(int)(SZ_WKV / 4 / 256), blk, 0, stream>>>(wk, wkb, SZ_WKV / 4);
    cvt_bf16<<<(int)(SZ_WKV / 4 / 256), blk, 0, stream>>>(wv, wvb, SZ_WKV / 4);
    cvt_bf16<<<(int)(SZ_W / 4 / 256), blk, 0, stream>>>(wo, wob, SZ_W / 4);

    // projections (global_load_lds GEMMs)
    gemm_fast<false><<<dim3(DIM / 128, M / 128), blk, 0, stream>>>(xb, wqb, qbuf, DIM, DIM);
    gemm_kv<<<dim3(16, M / 128), blk, 0, stream>>>(xb, wkb, wvb, kbuf, vbuf);

    // RoPE
    int totq = (int)(M * NH * 64);
    int totk = (int)(M * NKV * 64);
    rope_kernel<<<(totq + 255) / 256, blk, 0, stream>>>(qbuf, cosb, sinb, NH, totq);
    rope_kernel<<<(totk + 255) / 256, blk, 0, stream>>>(kbuf, cosb, sinb, NKV, totk);

    // attention
    flash_attn<<<dim3(NN / 128, NH, BB), blk, 0, stream>>>(qbuf, kbuf, vbuf, obuf);

    // output projection -> f32
    gemm_fast<true><<<dim3(DIM / 128, M / 128), blk, 0, stream>>>(obuf, wob, out, DIM, DIM);
  } else {
    // fallback: R3-proven f32-staging path (needs ~84 MB)
    uint16_t* qbuf = (uint16_t*)d_ws;
    uint16_t* kbuf = qbuf + SZ_Q;
    uint16_t* vbuf = kbuf + SZ_KV;
    uint16_t* obuf = vbuf + SZ_KV;

    gemm_bt<true, true, false><<<dim3(DIM / 128, M / 128), blk, 0, stream>>>(x, wq, qbuf, M, DIM, DIM);
    gemm_bt<true, true, false><<<dim3((NKV * HD) / 128, M / 128), blk, 0, stream>>>(x, wk, kbuf, M, NKV * HD, DIM);
    gemm_bt<true, true, false><<<dim3((NKV * HD) / 128, M / 128), blk, 0, stream>>>(x, wv, vbuf, M, NKV * HD, DIM);

    int totq = (int)(M * NH * 64);
    int totk = (int)(M * NKV * 64);
    rope_kernel<<<(totq + 255) / 256, blk, 0, stream>>>(qbuf, cosb, sinb, NH, totq);
    rope_kernel<<<(totk + 255) / 256, blk, 0, stream>>>(kbuf, cosb, sinb, NKV, totk);

    flash_attn<<<dim3(NN / 128, NH, BB), blk, 0, stream>>>(qbuf, kbuf, vbuf, obuf);

    gemm_bt<false, true, true><<<dim3(DIM / 128, M / 128), blk, 0, stream>>>(obuf, wo, out, M, DIM, DIM);
  }
}